// Round 1
// baseline (565.917 us; speedup 1.0000x reference)
//
#include <hip/hip_runtime.h>

#define B_      32
#define D_      128
#define N_      16384          // H*W
#define K_      32
#define NCHUNK  16             // n-chunks per batch
#define CSZ     (N_ / NCHUNK)  // 1024 n per block
#define TILE    64             // n per sub-tile
#define NSUB    (CSZ / TILE)   // 16 sub-tiles per block
#define XS_STRIDE 132          // 128 + 4 pad (keeps float4 alignment)
#define AS_STRIDE 36           // 32 + 4 pad

// ---- workspace layout (floats) ----
// [0, 4096)                cT[d][k]  (codewords transposed)
// [4096, 4128)             c2[k]
// [4608, 20992)            AsumP[512][32]
// [24576, 24576+512*4096)  Ep[512][32][128]
#define WS_CT     0
#define WS_C2     4096
#define WS_ASUMP  4608
#define WS_EP     24576

__global__ void prep_kernel(const float* __restrict__ cw, float* __restrict__ ws) {
    const int t = threadIdx.x;
    float* cT = ws + WS_CT;
    float* c2 = ws + WS_C2;
    for (int i = t; i < K_ * D_; i += 256) {
        const int k = i >> 7;       // i / 128
        const int d = i & 127;
        cT[d * K_ + k] = cw[i];
    }
    if (t < K_) {
        float s = 0.f;
#pragma unroll
        for (int d = 0; d < D_; ++d) {
            const float v = cw[t * D_ + d];
            s += v * v;
        }
        c2[t] = s;
    }
}

__global__ __launch_bounds__(256, 2) void main_kernel(
        const float* __restrict__ X,
        const float* __restrict__ scale,
        const float* __restrict__ ws_ro,   // cT, c2
        float* __restrict__ AsumP,
        float* __restrict__ Ep)
{
    __shared__ float Xs[TILE * XS_STRIDE];   // 33792 B
    __shared__ float As[TILE * AS_STRIDE];   //  9216 B

    const int t     = threadIdx.x;
    const int blk   = blockIdx.x;
    const int b     = blk / NCHUNK;
    const int chunk = blk % NCHUNK;
    const int n0    = chunk * CSZ;

    const float* cT = ws_ro + WS_CT;
    const float* c2 = ws_ro + WS_C2;

    // phase-1 mapping: lane = n within tile, wave = k-octet
    const int n_l = t & 63;
    const int kg  = __builtin_amdgcn_readfirstlane(t >> 6);   // wave-uniform 0..3
    // phase-2 mapping: 8 k-quads x 32 d-quads
    const int kq = t & 7;
    const int dg = t >> 3;

    float acc2[16];
#pragma unroll
    for (int i = 0; i < 16; ++i) acc2[i] = 0.f;
    float asum_part = 0.f;

    const float* Xb = X + (size_t)b * ((size_t)D_ * N_);

    for (int s = 0; s < NSUB; ++s) {
        const int ns = n0 + s * TILE;

        // ---------- phase 1: dot products (xc) ----------
        float acc[8];
#pragma unroll
        for (int j = 0; j < 8; ++j) acc[j] = 0.f;
        float x2 = 0.f;

        const float* Xr = Xb + ns + n_l;
#pragma unroll 2
        for (int d0 = 0; d0 < D_; d0 += 4) {
            float xb[4];
#pragma unroll
            for (int dd = 0; dd < 4; ++dd) {
                const float x = Xr[(size_t)(d0 + dd) * N_];   // coalesced: lanes = consecutive n
                xb[dd] = x;
                x2 += x * x;
                const float* crow = cT + (d0 + dd) * K_ + kg * 8;  // scalar (s_load) address
#pragma unroll
                for (int j = 0; j < 8; ++j) acc[j] += x * crow[j];
            }
            if ((d0 >> 5) == kg) {   // this wave stages its d-quarter of the tile
                *reinterpret_cast<float4*>(&Xs[n_l * XS_STRIDE + d0]) =
                    make_float4(xb[0], xb[1], xb[2], xb[3]);
            }
        }

        // scaled distances
        float sl[8];
#pragma unroll
        for (int j = 0; j < 8; ++j) {
            const int k = kg * 8 + j;
            sl[j] = scale[k] * (x2 - 2.f * acc[j] + c2[k]);
        }
        *reinterpret_cast<float4*>(&As[n_l * AS_STRIDE + kg * 8]) =
            make_float4(sl[0], sl[1], sl[2], sl[3]);
        *reinterpret_cast<float4*>(&As[n_l * AS_STRIDE + kg * 8 + 4]) =
            make_float4(sl[4], sl[5], sl[6], sl[7]);
        __syncthreads();   // Xs + sl visible

        // ---------- softmax over K=32 ----------
        float sall[32];
#pragma unroll
        for (int q = 0; q < 8; ++q) {
            const float4 v = *reinterpret_cast<const float4*>(&As[n_l * AS_STRIDE + q * 4]);
            sall[q * 4 + 0] = v.x; sall[q * 4 + 1] = v.y;
            sall[q * 4 + 2] = v.z; sall[q * 4 + 3] = v.w;
        }
        float m = sall[0];
#pragma unroll
        for (int i = 1; i < 32; ++i) m = fmaxf(m, sall[i]);
        float ssum = 0.f;
#pragma unroll
        for (int i = 0; i < 32; ++i) { sall[i] = __expf(sall[i] - m); ssum += sall[i]; }
        const float inv = 1.f / ssum;
        __syncthreads();   // everyone finished reading sl before overwrite
        *reinterpret_cast<float4*>(&As[n_l * AS_STRIDE + kg * 8]) =
            make_float4(sall[kg * 8 + 0] * inv, sall[kg * 8 + 1] * inv,
                        sall[kg * 8 + 2] * inv, sall[kg * 8 + 3] * inv);
        *reinterpret_cast<float4*>(&As[n_l * AS_STRIDE + kg * 8 + 4]) =
            make_float4(sall[kg * 8 + 4] * inv, sall[kg * 8 + 5] * inv,
                        sall[kg * 8 + 6] * inv, sall[kg * 8 + 7] * inv);
        __syncthreads();   // normalized A visible

        // ---------- Asum partials (distributed: t -> (k = t&31, j-block = t>>5)) ----------
        {
            const int kk = t & 31;
            const int jh = t >> 5;
#pragma unroll
            for (int jj = 0; jj < 8; ++jj)
                asum_part += As[(jh * 8 + jj) * AS_STRIDE + kk];
        }

        // ---------- phase 2: E[k][d] += A[n,k] * x[n,d] ----------
#pragma unroll 4
        for (int j = 0; j < TILE; ++j) {
            const float4 x4 = *reinterpret_cast<const float4*>(&Xs[j * XS_STRIDE + dg * 4]);
            const float4 a4 = *reinterpret_cast<const float4*>(&As[j * AS_STRIDE + kq * 4]);
            acc2[0]  += a4.x * x4.x;  acc2[1]  += a4.x * x4.y;
            acc2[2]  += a4.x * x4.z;  acc2[3]  += a4.x * x4.w;
            acc2[4]  += a4.y * x4.x;  acc2[5]  += a4.y * x4.y;
            acc2[6]  += a4.y * x4.z;  acc2[7]  += a4.y * x4.w;
            acc2[8]  += a4.z * x4.x;  acc2[9]  += a4.z * x4.y;
            acc2[10] += a4.z * x4.z;  acc2[11] += a4.z * x4.w;
            acc2[12] += a4.w * x4.x;  acc2[13] += a4.w * x4.y;
            acc2[14] += a4.w * x4.z;  acc2[15] += a4.w * x4.w;
        }
        __syncthreads();   // protect Xs/As before next sub-tile
    }

    // ---------- write per-block partials ----------
    float* EpB = Ep + (size_t)blk * (K_ * D_);
#pragma unroll
    for (int kk = 0; kk < 4; ++kk) {
        const int k = kq * 4 + kk;
        *reinterpret_cast<float4*>(&EpB[k * D_ + dg * 4]) =
            make_float4(acc2[kk * 4 + 0], acc2[kk * 4 + 1],
                        acc2[kk * 4 + 2], acc2[kk * 4 + 3]);
    }
    __syncthreads();
    As[t] = asum_part;     // reuse LDS for the 8-way Asum reduce
    __syncthreads();
    if (t < K_) {
        float s = 0.f;
#pragma unroll
        for (int jh = 0; jh < 8; ++jh) s += As[jh * 32 + t];
        AsumP[blk * K_ + t] = s;
    }
}

__global__ void finalize_kernel(const float* __restrict__ cw,
                                const float* __restrict__ AsumP,
                                const float* __restrict__ Ep,
                                float* __restrict__ out)
{
    const int idx = blockIdx.x * 256 + threadIdx.x;   // 131072 outputs
    const int d = idx & 127;
    const int k = (idx >> 7) & 31;
    const int b = idx >> 12;
    float s = 0.f;
    float asum = 0.f;
#pragma unroll
    for (int c = 0; c < NCHUNK; ++c) {
        const int blk = b * NCHUNK + c;
        s    += Ep[(size_t)blk * (K_ * D_) + k * D_ + d];
        asum += AsumP[blk * K_ + k];
    }
    out[idx] = s - asum * cw[k * D_ + d];
}

extern "C" void kernel_launch(void* const* d_in, const int* in_sizes, int n_in,
                              void* d_out, int out_size, void* d_ws, size_t ws_size,
                              hipStream_t stream) {
    const float* X     = (const float*)d_in[0];
    const float* cw    = (const float*)d_in[1];
    const float* scale = (const float*)d_in[2];
    float* out = (float*)d_out;
    float* ws  = (float*)d_ws;

    float* AsumP = ws + WS_ASUMP;
    float* Ep    = ws + WS_EP;

    prep_kernel<<<1, 256, 0, stream>>>(cw, ws);
    main_kernel<<<B_ * NCHUNK, 256, 0, stream>>>(X, scale, ws, AsumP, Ep);
    finalize_kernel<<<(B_ * K_ * D_) / 256, 256, 0, stream>>>(cw, AsumP, Ep, out);
}

// Round 2
// 435.148 us; speedup vs baseline: 1.3005x; 1.3005x over previous
//
#include <hip/hip_runtime.h>

#define B_      32
#define D_      128
#define N_      16384          // H*W
#define K_      32
#define NCHUNK  16             // n-chunks per batch
#define CSZ     (N_ / NCHUNK)  // 1024 n per block
#define NS      512            // n per sub-tile (= one thread per n)
#define NSUB    (CSZ / NS)     // 2 sub-tiles per block
#define AST_STRIDE 520         // 512 bf16 cols + 8 pad (row = 1040 B, 16B-aligned)

// ---- workspace layout (floats) ----
#define WS_CT    0             // cT[d][k]      4096
#define WS_SC    4096          // scale[k]        32
#define WS_SM2   4128          // -2*scale[k]     32
#define WS_C2S   4160          // scale[k]*c2[k]  32
#define WS_ASUMP 4352          // AsumP[512][32]
#define WS_EP    24576         // Ep[512][32][128]

typedef __attribute__((ext_vector_type(8))) short bf16x8;
typedef __attribute__((ext_vector_type(4))) float f32x4;

static __device__ inline unsigned short f2bf(float f) {
    unsigned int u = __float_as_uint(f);
    u += 0x7fffu + ((u >> 16) & 1u);        // RNE
    return (unsigned short)(u >> 16);
}

static __device__ inline bf16x8 pack8(float4 a, float4 b) {
    bf16x8 r;
    r[0] = (short)f2bf(a.x); r[1] = (short)f2bf(a.y);
    r[2] = (short)f2bf(a.z); r[3] = (short)f2bf(a.w);
    r[4] = (short)f2bf(b.x); r[5] = (short)f2bf(b.y);
    r[6] = (short)f2bf(b.z); r[7] = (short)f2bf(b.w);
    return r;
}

__global__ void prep_kernel(const float* __restrict__ cw,
                            const float* __restrict__ scale,
                            float* __restrict__ ws) {
    const int k = blockIdx.x;        // 32 blocks of 64 threads, one wave each
    const int l = threadIdx.x;
    float s = 0.f;
#pragma unroll
    for (int i = 0; i < 2; ++i) {
        const int d = l + i * 64;
        const float v = cw[k * D_ + d];
        s += v * v;
        ws[WS_CT + d * K_ + k] = v;
    }
#pragma unroll
    for (int o = 32; o > 0; o >>= 1) s += __shfl_down(s, o, 64);
    if (l == 0) {
        const float sc = scale[k];
        ws[WS_SC  + k] = sc;
        ws[WS_SM2 + k] = -2.f * sc;
        ws[WS_C2S + k] = sc * s;
    }
}

__global__ __launch_bounds__(512, 4) void main_kernel(
        const float* __restrict__ X,
        const float* __restrict__ ws_ro,
        float* __restrict__ AsumP,
        float* __restrict__ Ep)
{
    __shared__ __align__(16) unsigned short AsT[K_ * AST_STRIDE];  // 33280 B

    const int t     = threadIdx.x;          // 0..511
    const int blk   = blockIdx.x;
    const int b     = blk >> 4;
    const int chunk = blk & 15;
    const int n0    = chunk * CSZ;

    const float* cT  = ws_ro + WS_CT;
    const float* scv = ws_ro + WS_SC;
    const float* sm2 = ws_ro + WS_SM2;
    const float* c2s = ws_ro + WS_C2S;

    // phase-2 wave roles
    const int lane = t & 63;
    const int w    = t >> 6;                // 0..7
    const int kh   = w & 1;                 // k-half (16 rows)
    const int dq   = w >> 1;                // d-quarter (32 cols)
    const int mc   = lane & 15;
    const int q    = lane >> 4;

    const float* Xb = X + (size_t)b * ((size_t)D_ * N_);

    f32x4 accE0 = {0.f, 0.f, 0.f, 0.f};
    f32x4 accE1 = {0.f, 0.f, 0.f, 0.f};
    f32x4 accO  = {0.f, 0.f, 0.f, 0.f};

    bf16x8 ones;
#pragma unroll
    for (int i = 0; i < 8; ++i) ones[i] = (short)0x3F80;   // bf16 1.0

    for (int s = 0; s < NSUB; ++s) {
        const int ns = n0 + s * NS;

        // ---------- phase 1: dots, one thread = one n, all 32 k ----------
        float acc[K_];
#pragma unroll
        for (int k = 0; k < K_; ++k) acc[k] = 0.f;
        float x2 = 0.f;

        const float* Xr = Xb + ns + t;
#pragma unroll 1
        for (int d0 = 0; d0 < D_; d0 += 8) {
            float xv[8];
#pragma unroll
            for (int i = 0; i < 8; ++i) xv[i] = Xr[(size_t)(d0 + i) * N_];
#pragma unroll
            for (int i = 0; i < 8; ++i) {
                x2 = fmaf(xv[i], xv[i], x2);
                const float* cr = cT + (d0 + i) * K_;   // wave-uniform -> s_load
#pragma unroll
                for (int k = 0; k < K_; ++k) acc[k] = fmaf(xv[i], cr[k], acc[k]);
            }
        }

        // ---------- softmax over K=32, fully in-register ----------
        float m = -3.4e38f;
#pragma unroll
        for (int k = 0; k < K_; ++k) {
            acc[k] = fmaf(scv[k], x2, fmaf(sm2[k], acc[k], c2s[k]));
            m = fmaxf(m, acc[k]);
        }
        float ssum = 0.f;
#pragma unroll
        for (int k = 0; k < K_; ++k) { acc[k] = __expf(acc[k] - m); ssum += acc[k]; }
        const float inv = 1.f / ssum;
#pragma unroll
        for (int k = 0; k < K_; ++k)
            AsT[k * AST_STRIDE + t] = f2bf(acc[k] * inv);   // conflict-free b16 col write

        __syncthreads();   // AsT complete

        // ---------- phase 2: E[k][d] += A^T . X via MFMA (contracts n) ----------
#pragma unroll 2
        for (int ks = 0; ks < NS / 32; ++ks) {
            const int nloc = ks * 32 + q * 8;
            const bf16x8 af = *(const bf16x8*)&AsT[(kh * 16 + mc) * AST_STRIDE + nloc];

            if (dq == 0)   // Asum = A . ones, piggybacked on the matrix pipe
                accO = __builtin_amdgcn_mfma_f32_16x16x32_bf16(af, ones, accO, 0, 0, 0);

            const float* bp = Xb + (size_t)(dq * 32 + mc) * N_ + (ns + nloc);
            const float4 b0 = *(const float4*)bp;
            const float4 b1 = *(const float4*)(bp + 4);
            accE0 = __builtin_amdgcn_mfma_f32_16x16x32_bf16(af, pack8(b0, b1), accE0, 0, 0, 0);

            const float* bp2 = bp + (size_t)16 * N_;
            const float4 c0 = *(const float4*)bp2;
            const float4 c1 = *(const float4*)(bp2 + 4);
            accE1 = __builtin_amdgcn_mfma_f32_16x16x32_bf16(af, pack8(c0, c1), accE1, 0, 0, 0);
        }
        __syncthreads();   // protect AsT before next sub-tile
    }

    // ---------- epilogue: per-block partials ----------
    float* EpB = Ep + (size_t)blk * (K_ * D_);
#pragma unroll
    for (int r = 0; r < 4; ++r) {
        const int k = kh * 16 + q * 4 + r;     // C/D row = (lane>>4)*4 + reg
        const int d = dq * 32 + mc;            // C/D col = lane&15
        EpB[k * D_ + d]      = accE0[r];
        EpB[k * D_ + d + 16] = accE1[r];
    }
    if (dq == 0 && mc == 0) {
#pragma unroll
        for (int r = 0; r < 4; ++r)
            AsumP[blk * K_ + kh * 16 + q * 4 + r] = accO[r];
    }
}

__global__ void finalize_kernel(const float* __restrict__ cw,
                                const float* __restrict__ AsumP,
                                const float* __restrict__ Ep,
                                float* __restrict__ out)
{
    const int idx = blockIdx.x * 256 + threadIdx.x;   // 131072 outputs
    const int d = idx & 127;
    const int k = (idx >> 7) & 31;
    const int b = idx >> 12;
    float s = 0.f;
    float asum = 0.f;
#pragma unroll
    for (int c = 0; c < NCHUNK; ++c) {
        const int blk = b * NCHUNK + c;
        s    += Ep[(size_t)blk * (K_ * D_) + k * D_ + d];
        asum += AsumP[blk * K_ + k];
    }
    out[idx] = s - asum * cw[k * D_ + d];
}

extern "C" void kernel_launch(void* const* d_in, const int* in_sizes, int n_in,
                              void* d_out, int out_size, void* d_ws, size_t ws_size,
                              hipStream_t stream) {
    const float* X     = (const float*)d_in[0];
    const float* cw    = (const float*)d_in[1];
    const float* scale = (const float*)d_in[2];
    float* out = (float*)d_out;
    float* ws  = (float*)d_ws;

    float* AsumP = ws + WS_ASUMP;
    float* Ep    = ws + WS_EP;

    prep_kernel<<<K_, 64, 0, stream>>>(cw, scale, ws);
    main_kernel<<<B_ * NCHUNK, 512, 0, stream>>>(X, ws, AsumP, Ep);
    finalize_kernel<<<(B_ * K_ * D_) / 256, 256, 0, stream>>>(cw, AsumP, Ep, out);
}

// Round 3
// 422.677 us; speedup vs baseline: 1.3389x; 1.0295x over previous
//
#include <hip/hip_runtime.h>
#include <hip/hip_bf16.h>

#define B_   32
#define D_   128
#define N_   16384            // H*W
#define K_   32
#define NS   256              // n per sub-tile per block
#define AST_STRIDE 264        // bf16 units; 264*2=528B rows (16B-aligned), even 8dw/bank on b128

// ---- workspace layout (floats) ----
#define WS_WBF  0             // bf16 W[32][128] = -2*scale*log2e*cw  (2048 floats)
#define WS_SC   2048          // scale[k]*log2e (32)
#define WS_C2S  2080          // scale'[k]*||c_k||^2 (32)
#define WS_EP   2112          // Ep[NB][32][128], then AsumP[NB][32] after

typedef __attribute__((ext_vector_type(8))) short bf16x8;
typedef __attribute__((ext_vector_type(4))) float f32x4;

static __device__ inline unsigned int pk2(float lo, float hi) {
    __hip_bfloat162 h = __float22bfloat162_rn(make_float2(lo, hi));
    unsigned int r;
    __builtin_memcpy(&r, &h, 4);
    return r;
}

static __device__ inline bf16x8 pack8(const float* v) {
    union { unsigned int u[4]; bf16x8 f; } r;
    r.u[0] = pk2(v[0], v[1]);
    r.u[1] = pk2(v[2], v[3]);
    r.u[2] = pk2(v[4], v[5]);
    r.u[3] = pk2(v[6], v[7]);
    return r.f;
}

__global__ void prep_kernel(const float* __restrict__ cw,
                            const float* __restrict__ scale,
                            float* __restrict__ ws) {
    const int k = blockIdx.x;     // 32 blocks x 64 lanes
    const int l = threadIdx.x;
    const float sc = scale[k] * 1.44269504088896f;   // fold log2e
    unsigned short* Wbf = (unsigned short*)(ws + WS_WBF);
    float s = 0.f;
#pragma unroll
    for (int i = 0; i < 2; ++i) {
        const int d = l + i * 64;
        const float v = cw[k * D_ + d];
        s += v * v;
        const float w = -2.f * sc * v;
        unsigned int u = __float_as_uint(w);
        u += 0x7fffu + ((u >> 16) & 1u);
        Wbf[k * D_ + d] = (unsigned short)(u >> 16);
    }
#pragma unroll
    for (int o = 32; o > 0; o >>= 1) s += __shfl_down(s, o, 64);
    if (l == 0) {
        ws[WS_SC  + k] = sc;
        ws[WS_C2S + k] = sc * s;
    }
}

template<int NCHUNKT>
__global__ __launch_bounds__(256, 4) void main_kernel(
        const float* __restrict__ X,
        const float* __restrict__ ws_ro,
        float* __restrict__ AsumP,
        float* __restrict__ Ep)
{
    constexpr int CSZT  = N_ / NCHUNKT;
    constexpr int NSUBT = CSZT / NS;

    __shared__ __align__(16) unsigned short AsT[K_ * AST_STRIDE];  // 16896 B

    const int t    = threadIdx.x;
    const int lane = t & 63;
    const int w    = t >> 6;          // wave 0..3
    const int mc   = lane & 15;
    const int q    = lane >> 4;

    const int blk   = blockIdx.x;
    const int b     = blk / NCHUNKT;
    const int chunk = blk % NCHUNKT;
    const int n0    = chunk * CSZT;

    const float* Xb = X + (size_t)b * ((size_t)D_ * N_);

    // ---- persistent codeword A-frags: W[k = kb*16+mc][d = kd*32 + q*8 + j] ----
    const unsigned short* Wbf = (const unsigned short*)(ws_ro + WS_WBF);
    bf16x8 wf[2][4];
#pragma unroll
    for (int kb = 0; kb < 2; ++kb)
#pragma unroll
        for (int kd = 0; kd < 4; ++kd)
            wf[kb][kd] = *(const bf16x8*)&Wbf[(kb * 16 + mc) * D_ + kd * 32 + q * 8];

    // per-lane softmax constants for k = kb*16 + q*4 + r
    float scr[2][4], c2r[2][4];
#pragma unroll
    for (int kb = 0; kb < 2; ++kb)
#pragma unroll
        for (int r = 0; r < 4; ++r) {
            scr[kb][r] = ws_ro[WS_SC  + kb * 16 + q * 4 + r];
            c2r[kb][r] = ws_ro[WS_C2S + kb * 16 + q * 4 + r];
        }

    bf16x8 ones;
#pragma unroll
    for (int i = 0; i < 8; ++i) ones[i] = (short)0x3F80;

    f32x4 accE[2][2] = {{{0.f,0.f,0.f,0.f},{0.f,0.f,0.f,0.f}},
                        {{0.f,0.f,0.f,0.f},{0.f,0.f,0.f,0.f}}};
    f32x4 accO[2]    = {{0.f,0.f,0.f,0.f},{0.f,0.f,0.f,0.f}};

    for (int s = 0; s < NSUBT; ++s) {
        const int ns = n0 + s * NS;

        // ================= phase 1: xc via MFMA + in-register softmax =================
#pragma unroll 1
        for (int cb = 0; cb < 4; ++cb) {
            const int ntl = (w * 4 + cb) * 16;          // local n of this col-block
            const float* xp = Xb + ns + ntl + mc;       // column for this lane

            f32x4 S0 = {0.f,0.f,0.f,0.f};
            f32x4 S1 = {0.f,0.f,0.f,0.f};
            float x2 = 0.f;
#pragma unroll
            for (int kd = 0; kd < 4; ++kd) {
                float xv[8];
#pragma unroll
                for (int j = 0; j < 8; ++j)
                    xv[j] = xp[(size_t)(kd * 32 + q * 8 + j) * N_];  // 64B/quad segments
#pragma unroll
                for (int j = 0; j < 8; ++j) x2 = fmaf(xv[j], xv[j], x2);
                const bf16x8 xb = pack8(xv);
                S0 = __builtin_amdgcn_mfma_f32_16x16x32_bf16(wf[0][kd], xb, S0, 0, 0, 0);
                S1 = __builtin_amdgcn_mfma_f32_16x16x32_bf16(wf[1][kd], xb, S1, 0, 0, 0);
            }
            // x2: lane covered 32 of 128 d; sum over the q-groups
            x2 += __shfl_xor(x2, 16, 64);
            x2 += __shfl_xor(x2, 32, 64);

            // sl[k] (already scaled by log2e) for k = {q*4+r, 16+q*4+r}
            float sl[8];
#pragma unroll
            for (int r = 0; r < 4; ++r) {
                sl[r]     = fmaf(scr[0][r], x2, S0[r] + c2r[0][r]);
                sl[4 + r] = fmaf(scr[1][r], x2, S1[r] + c2r[1][r]);
            }
            float m = sl[0];
#pragma unroll
            for (int i = 1; i < 8; ++i) m = fmaxf(m, sl[i]);
            m = fmaxf(m, __shfl_xor(m, 16, 64));
            m = fmaxf(m, __shfl_xor(m, 32, 64));
            float ssum = 0.f;
#pragma unroll
            for (int i = 0; i < 8; ++i) { sl[i] = exp2f(sl[i] - m); ssum += sl[i]; }
            ssum += __shfl_xor(ssum, 16, 64);
            ssum += __shfl_xor(ssum, 32, 64);
            const float inv = 1.f / ssum;

            const int col = ntl + mc;
#pragma unroll
            for (int r = 0; r < 4; ++r) {
                const unsigned int u = pk2(sl[r] * inv, sl[4 + r] * inv);
                AsT[(q * 4 + r) * AST_STRIDE + col]        = (unsigned short)u;
                AsT[(16 + q * 4 + r) * AST_STRIDE + col]   = (unsigned short)(u >> 16);
            }
        }
        __syncthreads();   // AsT complete

        // ================= phase 2: E += A^T . X via MFMA (contracts n) =================
        const int dq = w;
#pragma unroll 2
        for (int ks = 0; ks < NS / 32; ++ks) {
            const int nl = ks * 32 + q * 8;
            const bf16x8 a0 = *(const bf16x8*)&AsT[mc * AST_STRIDE + nl];
            const bf16x8 a1 = *(const bf16x8*)&AsT[(16 + mc) * AST_STRIDE + nl];

            const float* bp = Xb + (size_t)(dq * 32 + mc) * N_ + ns + nl;
            float xr[8];
            *(float4*)&xr[0] = *(const float4*)bp;
            *(float4*)&xr[4] = *(const float4*)(bp + 4);
            const bf16x8 xb0 = pack8(xr);
            const float* bp2 = bp + (size_t)16 * N_;
            *(float4*)&xr[0] = *(const float4*)bp2;
            *(float4*)&xr[4] = *(const float4*)(bp2 + 4);
            const bf16x8 xb1 = pack8(xr);

            accE[0][0] = __builtin_amdgcn_mfma_f32_16x16x32_bf16(a0, xb0, accE[0][0], 0, 0, 0);
            accE[0][1] = __builtin_amdgcn_mfma_f32_16x16x32_bf16(a0, xb1, accE[0][1], 0, 0, 0);
            accE[1][0] = __builtin_amdgcn_mfma_f32_16x16x32_bf16(a1, xb0, accE[1][0], 0, 0, 0);
            accE[1][1] = __builtin_amdgcn_mfma_f32_16x16x32_bf16(a1, xb1, accE[1][1], 0, 0, 0);
            if (w == 0) {
                accO[0] = __builtin_amdgcn_mfma_f32_16x16x32_bf16(a0, ones, accO[0], 0, 0, 0);
                accO[1] = __builtin_amdgcn_mfma_f32_16x16x32_bf16(a1, ones, accO[1], 0, 0, 0);
            }
        }
        __syncthreads();   // done reading AsT before next sub-tile overwrites
    }

    // ---- epilogue: per-block partials ----
    float* EpB = Ep + (size_t)blk * (K_ * D_);
#pragma unroll
    for (int kh = 0; kh < 2; ++kh)
#pragma unroll
        for (int ds = 0; ds < 2; ++ds)
#pragma unroll
            for (int r = 0; r < 4; ++r) {
                const int k = kh * 16 + q * 4 + r;
                const int d = w * 32 + ds * 16 + mc;
                EpB[k * D_ + d] = accE[kh][ds][r];
            }
    if (w == 0 && mc == 0) {
#pragma unroll
        for (int kh = 0; kh < 2; ++kh)
#pragma unroll
            for (int r = 0; r < 4; ++r)
                AsumP[blk * K_ + kh * 16 + q * 4 + r] = accO[kh][r];
    }
}

template<int NCHUNKT>
__global__ void finalize_kernel(const float* __restrict__ cw,
                                const float* __restrict__ AsumP,
                                const float* __restrict__ Ep,
                                float* __restrict__ out)
{
    const int idx = blockIdx.x * 256 + threadIdx.x;   // 131072 outputs
    const int d = idx & 127;
    const int k = (idx >> 7) & 31;
    const int b = idx >> 12;
    float s = 0.f, asum = 0.f;
#pragma unroll
    for (int c = 0; c < NCHUNKT; ++c) {
        const int blk = b * NCHUNKT + c;
        s    += Ep[(size_t)blk * (K_ * D_) + k * D_ + d];
        asum += AsumP[blk * K_ + k];
    }
    out[idx] = s - asum * cw[k * D_ + d];
}

extern "C" void kernel_launch(void* const* d_in, const int* in_sizes, int n_in,
                              void* d_out, int out_size, void* d_ws, size_t ws_size,
                              hipStream_t stream) {
    const float* X     = (const float*)d_in[0];
    const float* cw    = (const float*)d_in[1];
    const float* scale = (const float*)d_in[2];
    float* out = (float*)d_out;
    float* ws  = (float*)d_ws;

    prep_kernel<<<K_, 64, 0, stream>>>(cw, scale, ws);

    const size_t need32 = (size_t)(WS_EP + 1024 * (K_ * D_) + 1024 * K_) * 4;
    if (ws_size >= need32) {
        float* Ep    = ws + WS_EP;
        float* AsumP = Ep + (size_t)1024 * (K_ * D_);
        main_kernel<32><<<B_ * 32, 256, 0, stream>>>(X, ws, AsumP, Ep);
        finalize_kernel<32><<<(B_ * K_ * D_) / 256, 256, 0, stream>>>(cw, AsumP, Ep, out);
    } else {
        float* Ep    = ws + WS_EP;
        float* AsumP = Ep + (size_t)512 * (K_ * D_);
        main_kernel<16><<<B_ * 16, 256, 0, stream>>>(X, ws, AsumP, Ep);
        finalize_kernel<16><<<(B_ * K_ * D_) / 256, 256, 0, stream>>>(cw, AsumP, Ep, out);
    }
}